// Round 13
// baseline (486.668 us; speedup 1.0000x reference)
//
#include <hip/hip_runtime.h>
#include <hip/hip_bf16.h>

using bf16 = __hip_bfloat16;
typedef __bf16 bf16x8 __attribute__((ext_vector_type(8)));
typedef __bf16 bf16x4 __attribute__((ext_vector_type(4)));
typedef float f32x4 __attribute__((ext_vector_type(4)));

#define AS1C(p) ((const __attribute__((address_space(1))) void*)(p))
#define AS3(p)  ((__attribute__((address_space(3))) void*)(p))

static constexpr int BM = 128, BN = 128, BK = 32;

// ---------------------------------------------------------------------------
__global__ __launch_bounds__(256)
void cvt_f32_bf16(const float* __restrict__ in, bf16* __restrict__ out) {
    int i = (blockIdx.x * 256 + threadIdx.x) * 4;
    float4 v = *reinterpret_cast<const float4*>(in + i);
    out[i + 0] = __float2bfloat16(v.x);
    out[i + 1] = __float2bfloat16(v.y);
    out[i + 2] = __float2bfloat16(v.z);
    out[i + 3] = __float2bfloat16(v.w);
}

// ---------------------------------------------------------------------------
__global__ __launch_bounds__(1024)
void transpose_w(const float* __restrict__ W, bf16* __restrict__ WT) {
    __shared__ float tile[32][33];
    int bx = blockIdx.x * 32, by = blockIdx.y * 32;
    tile[threadIdx.y][threadIdx.x] = W[(size_t)(by + threadIdx.y) * 1024 + bx + threadIdx.x];
    __syncthreads();
    WT[(size_t)(bx + threadIdx.y) * 1024 + by + threadIdx.x] =
        __float2bfloat16(tile[threadIdx.x][threadIdx.y]);
}

// ---------------------------------------------------------------------------
// V (B,H,L,128) bf16 -> VT (B,H,128,L) bf16
__global__ __launch_bounds__(1024)
void transpose_v(const bf16* __restrict__ V, bf16* __restrict__ VT) {
    __shared__ bf16 tile[32][33];
    const bf16* v = V + (size_t)blockIdx.z * 1024 * 128;
    bf16* vt = VT + (size_t)blockIdx.z * 1024 * 128;
    int l0 = blockIdx.x * 32, d0 = blockIdx.y * 32;
    tile[threadIdx.y][threadIdx.x] = v[(size_t)(l0 + threadIdx.y) * 128 + d0 + threadIdx.x];
    __syncthreads();
    vt[(size_t)(d0 + threadIdx.y) * 1024 + l0 + threadIdx.x] = tile[threadIdx.x][threadIdx.y];
}

// ---------------------------------------------------------------------------
// bf16 MFMA GEMM (validated): C = A @ Bt^T, 128x128 tile, 4 waves.
// MODE 0: QKV epilogue (N=3072 -> Q,K,V head-major bf16)
// MODE 3: C fp32 = acc + bias[n]
template<int MODE>
__global__ __launch_bounds__(256)
void gemm_bf16(const bf16* __restrict__ A, const bf16* __restrict__ Bt,
               float* __restrict__ C, const float* __restrict__ bias,
               int M, int N, int K, int lda, int ldb,
               bf16* __restrict__ Qb, bf16* __restrict__ Kb, bf16* __restrict__ Vb)
{
    __shared__ __align__(16) bf16 As[4 * BM * 8];
    __shared__ __align__(16) bf16 Bs[4 * BN * 8];
    const int t = threadIdx.x;
    const int lane = t & 63;
    const int wid = t >> 6;
    const int wm = wid >> 1, wn = wid & 1;
    const int bm0 = blockIdx.x * BM, bn0 = blockIdx.y * BN;

    f32x4 acc[4][4] = {};
    const int gl = lane >> 4, rl = lane & 15;

    for (int k0 = 0; k0 < K; k0 += BK) {
#pragma unroll
        for (int r = 0; r < 2; ++r) {
            int vt = r * 256 + t;
            int gg = vt >> 7, row = vt & 127;
            __builtin_amdgcn_global_load_lds(
                AS1C(A + (size_t)(bm0 + row) * lda + k0 + gg * 8),
                AS3(&As[(size_t)(r * 256 + (t & ~63)) * 8]), 16, 0, 0);
            __builtin_amdgcn_global_load_lds(
                AS1C(Bt + (size_t)(bn0 + row) * ldb + k0 + gg * 8),
                AS3(&Bs[(size_t)(r * 256 + (t & ~63)) * 8]), 16, 0, 0);
        }
        __syncthreads();
        bf16x8 af[4], bfr[4];
#pragma unroll
        for (int m = 0; m < 4; ++m)
            af[m] = *reinterpret_cast<const bf16x8*>(&As[(size_t)(gl * BM + wm * 64 + m * 16 + rl) * 8]);
#pragma unroll
        for (int n = 0; n < 4; ++n)
            bfr[n] = *reinterpret_cast<const bf16x8*>(&Bs[(size_t)(gl * BN + wn * 64 + n * 16 + rl) * 8]);
#pragma unroll
        for (int m = 0; m < 4; ++m)
#pragma unroll
            for (int n = 0; n < 4; ++n)
                acc[m][n] = __builtin_amdgcn_mfma_f32_16x16x32_bf16(af[m], bfr[n], acc[m][n], 0, 0, 0);
        __syncthreads();
    }

#pragma unroll
    for (int m = 0; m < 4; ++m) {
#pragma unroll
        for (int n = 0; n < 4; ++n) {
#pragma unroll
            for (int i = 0; i < 4; ++i) {
                int gm = bm0 + wm * 64 + m * 16 + gl * 4 + i;
                int gn = bn0 + wn * 64 + n * 16 + rl;
                float v = acc[m][n][i];
                if constexpr (MODE == 0) {
                    int which = gn >> 10, c = gn & 1023;
                    int h = c >> 7, d = c & 127;
                    int b = gm >> 10, l = gm & 1023;
                    bf16* dst = which == 0 ? Qb : (which == 1 ? Kb : Vb);
                    dst[(((size_t)(b * 8 + h) * 1024 + l) << 7) + d] = __float2bfloat16(v);
                } else {
                    C[(size_t)gm * (size_t)N + gn] = v + bias[gn];
                }
            }
        }
    }
}

// ---------------------------------------------------------------------------
// Fused attention, v3: QB=16 rows/block, 256 threads (4 waves), ~35 KB LDS
// -> 4 blocks/CU (phase-decorrelated). Mask exp hoisted to registers (bf16)
// BEFORE QK^T so the trans-pipe work and HBM mask read overlap MFMA.
// Renorm skipped (blend sums to 1 exactly).
__global__ __launch_bounds__(256, 4)
void fused_attn(const bf16* __restrict__ Qb, const bf16* __restrict__ Kb,
                const bf16* __restrict__ VTb, const float* __restrict__ mask,
                const float* __restrict__ gating,
                float* __restrict__ attn, bf16* __restrict__ Ob)
{
    constexpr int QB = 16;
    constexpr int SSTR = 1032;                    // bf16 units/row
    __shared__ __align__(16) bf16 S[QB * SSTR];   // 33 KB
    __shared__ float red0[QB][16];
    __shared__ float red1[QB][16];
    __shared__ float rowmax[QB], rowss[QB], rowsm[QB];

    const int tid  = threadIdx.x;
    const int lane = tid & 63, w = tid >> 6;      // 4 waves
    const int rl = lane & 15, gl = lane >> 4;
    const int qb = blockIdx.x, bh = blockIdx.y;
    const int b = bh >> 3, h = bh & 7;
    const int q0 = qb * QB;
    const float g = 1.f / (1.f + __expf(-gating[h]));

    const bf16* Qh  = Qb  + (size_t)bh * 1024 * 128;
    const bf16* Kh  = Kb  + (size_t)bh * 1024 * 128;
    const bf16* VTh = VTb + (size_t)bh * 128 * 1024;
    const float* maskh = mask + (size_t)bh * 1024 * 1024;
    float* attnh = attn + (size_t)bh * 1024 * 1024;

    // ---- Phase 0: mask row -> exp -> bf16 regs (overlaps later MFMA) ----
    const int r  = tid >> 4;     // 0..15 (row)
    const int c0 = tid & 15;     // col-chunk
    float msum = 0.f;
    bf16x4 em[16];
#pragma unroll
    for (int j = 0; j < 16; ++j) {
        float4 f = *reinterpret_cast<const float4*>(
            &maskh[(size_t)(q0 + r) * 1024 + c0 * 4 + j * 64]);
        float e0 = __expf(f.x), e1 = __expf(f.y), e2 = __expf(f.z), e3 = __expf(f.w);
        msum += e0 + e1 + e2 + e3;
        bf16x4 e; e[0] = (__bf16)e0; e[1] = (__bf16)e1; e[2] = (__bf16)e2; e[3] = (__bf16)e3;
        em[j] = e;
    }

    // ---- Phase 1: Q fragments (16 rows) ----
    bf16x8 qf[4];
#pragma unroll
    for (int ks = 0; ks < 4; ++ks)
        qf[ks] = *reinterpret_cast<const bf16x8*>(
            Qh + (size_t)(q0 + rl) * 128 + ks * 32 + gl * 8);

    // ---- Phase 2: S tiles; wave w owns t in [w*256, w*256+256) ----
    const int t0 = w * 256;
    bf16x8 kf[4], kn[4];
#pragma unroll
    for (int ks = 0; ks < 4; ++ks)
        kf[ks] = *reinterpret_cast<const bf16x8*>(
            Kh + (size_t)(t0 + rl) * 128 + ks * 32 + gl * 8);
#pragma unroll
    for (int nf = 0; nf < 16; ++nf) {
        const int tb = t0 + nf * 16;
        if (nf < 15) {
#pragma unroll
            for (int ks = 0; ks < 4; ++ks)
                kn[ks] = *reinterpret_cast<const bf16x8*>(
                    Kh + (size_t)(tb + 16 + rl) * 128 + ks * 32 + gl * 8);
        }
        f32x4 acc = {};
#pragma unroll
        for (int ks = 0; ks < 4; ++ks)
            acc = __builtin_amdgcn_mfma_f32_16x16x32_bf16(qf[ks], kf[ks], acc, 0, 0, 0);
#pragma unroll
        for (int i = 0; i < 4; ++i)
            S[(size_t)(gl * 4 + i) * SSTR + tb + rl] = __float2bfloat16(acc[i] * 0.03125f);
#pragma unroll
        for (int ks = 0; ks < 4; ++ks) kf[ks] = kn[ks];
    }
    __syncthreads();

    // ---- Phase 3: softmax + blend ----
    float mx = -1e30f;
#pragma unroll
    for (int j = 0; j < 8; ++j) {
        bf16x8 v = *reinterpret_cast<const bf16x8*>(&S[(size_t)r * SSTR + c0 * 8 + j * 128]);
#pragma unroll
        for (int e = 0; e < 8; ++e) mx = fmaxf(mx, (float)v[e]);
    }
    red0[r][c0] = mx;
    __syncthreads();
    if (tid < 16) {
        float m = red0[tid][0];
#pragma unroll
        for (int k = 1; k < 16; ++k) m = fmaxf(m, red0[tid][k]);
        rowmax[tid] = m;
    }
    __syncthreads();
    mx = rowmax[r];

    float ssum = 0.f;
#pragma unroll
    for (int j = 0; j < 8; ++j) {
        bf16x8 v = *reinterpret_cast<const bf16x8*>(&S[(size_t)r * SSTR + c0 * 8 + j * 128]);
        bf16x8 ev;
#pragma unroll
        for (int e = 0; e < 8; ++e) {
            float x = __expf((float)v[e] - mx);
            ssum += x;
            ev[e] = (__bf16)x;
        }
        *reinterpret_cast<bf16x8*>(&S[(size_t)r * SSTR + c0 * 8 + j * 128]) = ev;
    }
    red0[r][c0] = ssum; red1[r][c0] = msum;
    __syncthreads();
    if (tid < 16) {
        float a = 0.f, m2 = 0.f;
#pragma unroll
        for (int k = 0; k < 16; ++k) { a += red0[tid][k]; m2 += red1[tid][k]; }
        rowss[tid] = a; rowsm[tid] = m2;
    }
    __syncthreads();
    const float cp = (1.f - g) / rowss[r];
    const float cm = g / rowsm[r];
    float* arow = attnh + (size_t)(q0 + r) * 1024;
#pragma unroll
    for (int j = 0; j < 16; ++j) {
        const int c = c0 * 4 + j * 64;
        bf16x4 ev = *reinterpret_cast<const bf16x4*>(&S[(size_t)r * SSTR + c]);
        bf16x4 e = em[j];
        float a0 = cp * (float)ev[0] + cm * (float)e[0];
        float a1 = cp * (float)ev[1] + cm * (float)e[1];
        float a2 = cp * (float)ev[2] + cm * (float)e[2];
        float a3 = cp * (float)ev[3] + cm * (float)e[3];
        float4 o; o.x = a0; o.y = a1; o.z = a2; o.w = a3;
        *reinterpret_cast<float4*>(&arow[c]) = o;
        bf16x4 sb; sb[0] = (__bf16)a0; sb[1] = (__bf16)a1; sb[2] = (__bf16)a2; sb[3] = (__bf16)a3;
        *reinterpret_cast<bf16x4*>(&S[(size_t)r * SSTR + c]) = sb;
    }

    // ---- Phase 4: O = attn @ V. wave w owns d in [w*32, w*32+32) ----
    const int d0 = w * 32;
    bf16x8 vfA, vfB, vnA, vnB;
    vfA = *reinterpret_cast<const bf16x8*>(VTh + (size_t)(d0 + rl)      * 1024 + gl * 8);
    vfB = *reinterpret_cast<const bf16x8*>(VTh + (size_t)(d0 + 16 + rl) * 1024 + gl * 8);
    __syncthreads();
    f32x4 oaccA = {}, oaccB = {};
#pragma unroll
    for (int ks = 0; ks < 32; ++ks) {
        if (ks < 31) {
            vnA = *reinterpret_cast<const bf16x8*>(
                VTh + (size_t)(d0 + rl)      * 1024 + (ks + 1) * 32 + gl * 8);
            vnB = *reinterpret_cast<const bf16x8*>(
                VTh + (size_t)(d0 + 16 + rl) * 1024 + (ks + 1) * 32 + gl * 8);
        }
        bf16x8 a = *reinterpret_cast<const bf16x8*>(&S[(size_t)rl * SSTR + ks * 32 + gl * 8]);
        oaccA = __builtin_amdgcn_mfma_f32_16x16x32_bf16(a, vfA, oaccA, 0, 0, 0);
        oaccB = __builtin_amdgcn_mfma_f32_16x16x32_bf16(a, vfB, oaccB, 0, 0, 0);
        vfA = vnA; vfB = vnB;
    }
    bf16* obrow = Ob + ((size_t)b * 1024 + q0) * 1024 + h * 128;
#pragma unroll
    for (int i = 0; i < 4; ++i) {
        obrow[(size_t)(gl * 4 + i) * 1024 + d0 + rl]      = __float2bfloat16(oaccA[i]);
        obrow[(size_t)(gl * 4 + i) * 1024 + d0 + 16 + rl] = __float2bfloat16(oaccB[i]);
    }
}

// ---------------------------------------------------------------------------
extern "C" void kernel_launch(void* const* d_in, const int* in_sizes, int n_in,
                              void* d_out, int out_size, void* d_ws, size_t ws_size,
                              hipStream_t stream)
{
    const float* x      = (const float*)d_in[0];
    const float* mask   = (const float*)d_in[1];
    const float* Wq     = (const float*)d_in[2];
    const float* Wk     = (const float*)d_in[3];
    const float* Wv     = (const float*)d_in[4];
    const float* Wp     = (const float*)d_in[5];
    const float* bp     = (const float*)d_in[6];
    const float* gating = (const float*)d_in[7];

    float* out      = (float*)d_out;                 // (B,L,D) = 4M fp32
    float* attn_out = out + (size_t)4 * 1024 * 1024; // (B,H,L,L) = 32M fp32

    char* w = (char*)d_ws;   // 48 MiB peak
    bf16* xb  = (bf16*)(w);                        // [0,8MiB)   steps 1-3
    bf16* Ob  = (bf16*)(w);                        // [0,8MiB)   steps 6-7 (xb dead)
    bf16* WT  = (bf16*)(w + ((size_t)8  << 20));   // [8,16MiB)
    bf16* Qb  = (bf16*)(w + ((size_t)16 << 20));
    bf16* Kb  = (bf16*)(w + ((size_t)24 << 20));
    bf16* Vb  = (bf16*)(w + ((size_t)32 << 20));
    bf16* VTb = (bf16*)(w + ((size_t)40 << 20));

    const int ONE_M = 1024 * 1024;

    cvt_f32_bf16<<<4096, 256, 0, stream>>>(x, xb);
    dim3 tb(32, 32), tg(32, 32);
    transpose_w<<<tg, tb, 0, stream>>>(Wq, WT + 0 * ONE_M);
    transpose_w<<<tg, tb, 0, stream>>>(Wk, WT + 1 * ONE_M);
    transpose_w<<<tg, tb, 0, stream>>>(Wv, WT + 2 * ONE_M);
    transpose_w<<<tg, tb, 0, stream>>>(Wp, WT + 3 * ONE_M);
    gemm_bf16<0><<<dim3(32, 24, 1), 256, 0, stream>>>(
        xb, WT, nullptr, nullptr, 4096, 3072, 1024, 1024, 1024, Qb, Kb, Vb);
    transpose_v<<<dim3(32, 4, 32), tb, 0, stream>>>(Vb, VTb);
    fused_attn<<<dim3(64, 32), 256, 0, stream>>>(
        Qb, Kb, VTb, mask, gating, attn_out, Ob);
    gemm_bf16<3><<<dim3(32, 8, 1), 256, 0, stream>>>(
        Ob, WT + 3 * ONE_M, out, bp, 4096, 1024, 1024, 1024, 1024,
        nullptr, nullptr, nullptr);
}